// Round 1
// baseline (492.116 us; speedup 1.0000x reference)
//
#include <hip/hip_runtime.h>

typedef __attribute__((ext_vector_type(8))) short short8;
typedef __attribute__((ext_vector_type(4))) float f32x4;
typedef __attribute__((ext_vector_type(4))) unsigned short u16x4;
typedef unsigned short ushort_t;

#define GLOAD16(gp, sp) __builtin_amdgcn_global_load_lds( \
    (const __attribute__((address_space(1))) void*)(gp),  \
    (__attribute__((address_space(3))) void*)(sp), 16, 0, 0)

__device__ __forceinline__ ushort_t f2b(float f) {
    union { float f; unsigned u; } c; c.f = f;
    unsigned r = (c.u + 0x7FFFu + ((c.u >> 16) & 1u)) >> 16;
    return (ushort_t)r;
}
__device__ __forceinline__ float b2f(ushort_t u) {
    union { unsigned u; float f; } c; c.u = ((unsigned)u) << 16;
    return c.f;
}

// ---------------- fp32 -> bf16 convert ----------------
__global__ void cvt_bf16(const float* __restrict__ in, ushort_t* __restrict__ out, int n) {
    int i = (blockIdx.x * 256 + threadIdx.x) * 4;
    if (i < n) {
        f32x4 v = *(const f32x4*)(in + i);
        u16x4 o;
        #pragma unroll
        for (int j = 0; j < 4; j++) o[j] = f2b(v[j]);
        *(u16x4*)(out + i) = o;
    }
}

// ---------------- fp32 [R][Cc] -> bf16 [Cc][R] transpose ----------------
__global__ __launch_bounds__(256) void transpose_cvt(const float* __restrict__ in,
                                                     ushort_t* __restrict__ out,
                                                     int R, int Cc) {
    __shared__ float tile[32][33];
    int tx = threadIdx.x & 31, ty = threadIdx.x >> 5;
    int c0 = blockIdx.x * 32, r0 = blockIdx.y * 32;
    #pragma unroll
    for (int i = 0; i < 32; i += 8)
        tile[ty + i][tx] = in[(size_t)(r0 + ty + i) * Cc + c0 + tx];
    __syncthreads();
    #pragma unroll
    for (int i = 0; i < 32; i += 8)
        out[(size_t)(c0 + ty + i) * R + r0 + tx] = f2b(tile[tx][ty + i]);
}

// ---------------- bf16 GEMM: C[M][N] = A[M][K] * Bt[N][K]^T ----------------
// m97-style: 128x128 tile, BK=32, 4 waves (2x2), 4x4 16x16 frags per wave,
// global_load_lds width 16, 2 barriers per K-step.
template <bool F32OUT, bool BIAS>
__global__ __launch_bounds__(256) void gemm_bt(const ushort_t* __restrict__ A,
                                               const ushort_t* __restrict__ Bt,
                                               void* __restrict__ Cout,
                                               const float* __restrict__ bias,
                                               int M, int N, int K) {
    __shared__ ushort_t lA[128 * 32];
    __shared__ ushort_t lB[128 * 32];
    const int tid = threadIdx.x;
    const int l = tid & 63, wv = tid >> 6;
    const int g = l >> 4, q16 = l & 15;
    const int m0 = blockIdx.y * 128, n0 = blockIdx.x * 128;
    const int wr = wv >> 1, wc = wv & 1;

    f32x4 acc[4][4];
    #pragma unroll
    for (int i = 0; i < 4; i++)
        #pragma unroll
        for (int j = 0; j < 4; j++) acc[i][j] = (f32x4){0.f, 0.f, 0.f, 0.f};

    // staging: wave wv stages rows [wv*32, wv*32+32) of both tiles, 2 insts each
    const ushort_t* ga = A + (size_t)(m0 + wv * 32 + (l >> 2)) * K + (l & 3) * 8;
    const ushort_t* gb = Bt + (size_t)(n0 + wv * 32 + (l >> 2)) * K + (l & 3) * 8;
    ushort_t* sa = lA + wv * 32 * 32;
    ushort_t* sb = lB + wv * 32 * 32;

    for (int k0 = 0; k0 < K; k0 += 32) {
        __syncthreads();  // previous iter's reads done before overwrite
        GLOAD16(ga + k0, sa);
        GLOAD16(ga + k0 + (size_t)16 * K, sa + 16 * 32);
        GLOAD16(gb + k0, sb);
        GLOAD16(gb + k0 + (size_t)16 * K, sb + 16 * 32);
        __syncthreads();  // compiler drains vmcnt before barrier

        short8 af[4], bf[4];
        #pragma unroll
        for (int mi = 0; mi < 4; mi++)
            af[mi] = *(const short8*)(lA + (wr * 64 + mi * 16 + q16) * 32 + g * 8);
        #pragma unroll
        for (int ni = 0; ni < 4; ni++)
            bf[ni] = *(const short8*)(lB + (wc * 64 + ni * 16 + q16) * 32 + g * 8);
        #pragma unroll
        for (int mi = 0; mi < 4; mi++)
            #pragma unroll
            for (int ni = 0; ni < 4; ni++)
                acc[mi][ni] = __builtin_amdgcn_mfma_f32_16x16x32_bf16(
                    af[mi], bf[ni], acc[mi][ni], 0, 0, 0);
    }

    // epilogue: D frag: col = lane&15 (n), row = (lane>>4)*4 + r (m)
    #pragma unroll
    for (int ni = 0; ni < 4; ni++) {
        const int n = n0 + wc * 64 + ni * 16 + q16;
        float bv = 0.f;
        if (BIAS) bv = bias[n];
        #pragma unroll
        for (int mi = 0; mi < 4; mi++) {
            const int mbase = m0 + wr * 64 + mi * 16 + g * 4;
            #pragma unroll
            for (int r = 0; r < 4; r++) {
                if (F32OUT) {
                    ((float*)Cout)[(size_t)(mbase + r) * N + n] = acc[mi][ni][r] + bv;
                } else {
                    ((ushort_t*)Cout)[(size_t)(mbase + r) * N + n] = f2b(acc[mi][ni][r]);
                }
            }
        }
    }
}

// ---------------- RoPE + reshape: qkv[4096][3072] -> Qr/Kr [BH][T][64], Vt [BH][64][T] ----------------
__global__ void rope_scatter(const ushort_t* __restrict__ qkv,
                             const float* __restrict__ cosT, const float* __restrict__ sinT,
                             ushort_t* __restrict__ Qr, ushort_t* __restrict__ Kr,
                             ushort_t* __restrict__ Vt) {
    int tid = blockIdx.x * 256 + threadIdx.x;  // 524288 total
    // ---- q/k part: dc fastest for coalesced reads ----
    {
        int dc = tid & 7;
        int bht = tid >> 3;
        int t = bht & 2047, bh = bht >> 11;
        int b = bh >> 4, h = bh & 15;
        size_t mrow = ((size_t)b * 2048 + t) * 3072;
        short8 qv = *(const short8*)(qkv + mrow + h * 64 + dc * 8);
        short8 kv = *(const short8*)(qkv + mrow + 1024 + h * 64 + dc * 8);
        f32x4 cv = *(const f32x4*)(cosT + t * 32 + dc * 4);
        f32x4 sv = *(const f32x4*)(sinT + t * 32 + dc * 4);
        short8 qo, ko;
        #pragma unroll
        for (int j = 0; j < 4; j++) {
            float qe = b2f((ushort_t)qv[2 * j]), qod = b2f((ushort_t)qv[2 * j + 1]);
            float ke = b2f((ushort_t)kv[2 * j]), kod = b2f((ushort_t)kv[2 * j + 1]);
            qo[2 * j]     = (short)f2b(qe * cv[j] - qod * sv[j]);
            qo[2 * j + 1] = (short)f2b(qe * sv[j] + qod * cv[j]);
            ko[2 * j]     = (short)f2b(ke * cv[j] - kod * sv[j]);
            ko[2 * j + 1] = (short)f2b(ke * sv[j] + kod * cv[j]);
        }
        *(short8*)(Qr + ((size_t)bh * 2048 + t) * 64 + dc * 8) = qo;
        *(short8*)(Kr + ((size_t)bh * 2048 + t) * 64 + dc * 8) = ko;
    }
    // ---- v part: t fastest for coalesced transposed writes ----
    {
        int t = tid & 2047;
        int rest = tid >> 11;
        int dc = rest & 7, bh = rest >> 3;
        int b = bh >> 4, h = bh & 15;
        const ushort_t* vs = qkv + ((size_t)b * 2048 + t) * 3072 + 2048 + h * 64 + dc * 8;
        #pragma unroll
        for (int j = 0; j < 8; j++)
            Vt[((size_t)bh * 64 + dc * 8 + j) * 2048 + t] = vs[j];
    }
}

// ---------------- causal flash attention ----------------
// 4 waves/block, 16 q-rows/wave, KVBLK=32. Swapped QK^T (St = K @ Q^T) so the
// P-row is lane-local; PV uses a key-permuted contraction so St D-frags feed
// the PV B-frag directly (permutation applied identically to V^T A-frag loads).
__global__ __launch_bounds__(256) void attn_fwd(const ushort_t* __restrict__ Qr,
                                                const ushort_t* __restrict__ Kr,
                                                const ushort_t* __restrict__ Vt,
                                                ushort_t* __restrict__ Aout) {
    const int tid = threadIdx.x;
    const int l = tid & 63, wv = tid >> 6;
    const int g = l >> 4, q16 = l & 15;
    const int qt = blockIdx.x & 31, bh = blockIdx.x >> 5;
    const int qrow = qt * 64 + wv * 16;
    const int qpos = qrow + q16;
    const float LOG2E = 1.4426950408889634f;

    const ushort_t* Qp = Qr + ((size_t)bh * 2048 + qpos) * 64 + g * 8;
    short8 qf0 = *(const short8*)(Qp);
    short8 qf1 = *(const short8*)(Qp + 32);

    const ushort_t* Kb = Kr + (size_t)bh * 2048 * 64;
    const ushort_t* Vb = Vt + (size_t)bh * 64 * 2048;

    float mrun = -INFINITY, lsum = 0.f;
    f32x4 ot[4];
    #pragma unroll
    for (int c = 0; c < 4; c++) ot[c] = (f32x4){0.f, 0.f, 0.f, 0.f};

    for (int kvb = 0; kvb <= qrow + 15; kvb += 32) {
        // St tiles: rows = key (A-frag from K rows), cols = q (B-frag = Q^T)
        const ushort_t* kp0 = Kb + (size_t)(kvb + q16) * 64 + g * 8;
        const ushort_t* kp1 = kp0 + 16 * 64;
        f32x4 st0 = (f32x4){0.f, 0.f, 0.f, 0.f};
        f32x4 st1 = (f32x4){0.f, 0.f, 0.f, 0.f};
        st0 = __builtin_amdgcn_mfma_f32_16x16x32_bf16(*(const short8*)kp0, qf0, st0, 0, 0, 0);
        st0 = __builtin_amdgcn_mfma_f32_16x16x32_bf16(*(const short8*)(kp0 + 32), qf1, st0, 0, 0, 0);
        st1 = __builtin_amdgcn_mfma_f32_16x16x32_bf16(*(const short8*)kp1, qf0, st1, 0, 0, 0);
        st1 = __builtin_amdgcn_mfma_f32_16x16x32_bf16(*(const short8*)(kp1 + 32), qf1, st1, 0, 0, 0);

        // scale + causal mask + tile max (lane's q = q16; keys: kvb + t*16 + g*4 + r)
        float sv[8];
        float sm = -INFINITY;
        #pragma unroll
        for (int t = 0; t < 2; t++)
            #pragma unroll
            for (int r = 0; r < 4; r++) {
                int key = kvb + t * 16 + g * 4 + r;
                float s = (t ? st1[r] : st0[r]) * 0.125f;
                s = (key > qpos) ? -INFINITY : s;
                sv[t * 4 + r] = s;
                sm = fmaxf(sm, s);
            }
        sm = fmaxf(sm, __shfl_xor(sm, 16));
        sm = fmaxf(sm, __shfl_xor(sm, 32));
        float mnew = fmaxf(mrun, sm);
        float corr = exp2f((mrun - mnew) * LOG2E);
        mrun = mnew;

        float lsub = 0.f;
        short8 pf;
        #pragma unroll
        for (int i = 0; i < 8; i++) {
            float p = exp2f((sv[i] - mnew) * LOG2E);
            lsub += p;
            pf[i] = (short)f2b(p);
        }
        lsum = lsum * corr + lsub;

        // PV: Ot[d][q] += V^T[d][k] * P^T[k][q], k-permutation:
        // k = g*8+j -> key = kvb + (j>=4)*16 + g*4 + (j&3)  (same on both operands)
        #pragma unroll
        for (int c = 0; c < 4; c++) {
            #pragma unroll
            for (int r = 0; r < 4; r++) ot[c][r] *= corr;
            const ushort_t* vp = Vb + ((size_t)(c * 16 + q16)) * 2048 + kvb + g * 4;
            u16x4 v0 = *(const u16x4*)(vp);
            u16x4 v1 = *(const u16x4*)(vp + 16);
            short8 vf;
            #pragma unroll
            for (int j = 0; j < 4; j++) { vf[j] = (short)v0[j]; vf[4 + j] = (short)v1[j]; }
            ot[c] = __builtin_amdgcn_mfma_f32_16x16x32_bf16(vf, pf, ot[c], 0, 0, 0);
        }
    }

    lsum += __shfl_xor(lsum, 16);
    lsum += __shfl_xor(lsum, 32);
    float rinv = 1.f / lsum;

    const int b = bh >> 4, h = bh & 15;
    #pragma unroll
    for (int c = 0; c < 4; c++) {
        u16x4 ov;
        #pragma unroll
        for (int r = 0; r < 4; r++) ov[r] = f2b(ot[c][r] * rinv);
        *(u16x4*)(Aout + ((size_t)(b * 2048 + qpos)) * 1024 + h * 64 + c * 16 + g * 4) = ov;
    }
}

// ---------------- launch ----------------
extern "C" void kernel_launch(void* const* d_in, const int* in_sizes, int n_in,
                              void* d_out, int out_size, void* d_ws, size_t ws_size,
                              hipStream_t stream) {
    const float* x     = (const float*)d_in[0];
    const float* Wqkv  = (const float*)d_in[1];
    const float* Wproj = (const float*)d_in[2];
    const float* bproj = (const float*)d_in[3];
    const float* cosT  = (const float*)d_in[4];
    const float* sinT  = (const float*)d_in[5];

    char* ws = (char*)d_ws;
    ushort_t* xb     = (ushort_t*)(ws);                  //  8 MB  [0,8)
    ushort_t* WqkvT  = (ushort_t*)(ws + (8u  << 20));    //  6 MB  [8,14)
    ushort_t* WprojT = (ushort_t*)(ws + (14u << 20));    //  2 MB  [14,16)
    ushort_t* qkv    = (ushort_t*)(ws + (16u << 20));    // 24 MB  [16,40)
    ushort_t* Qr     = (ushort_t*)(ws + (40u << 20));    //  8 MB  [40,48)
    ushort_t* Kr     = (ushort_t*)(ws + (48u << 20));    //  8 MB  [48,56)
    ushort_t* Vt     = (ushort_t*)(ws + (56u << 20));    //  8 MB  [56,64)
    ushort_t* aout   = (ushort_t*)(ws + (64u << 20));    //  8 MB  [64,72)

    cvt_bf16<<<4096, 256, 0, stream>>>(x, xb, 4096 * 1024);
    transpose_cvt<<<dim3(96, 32), 256, 0, stream>>>(Wqkv, WqkvT, 1024, 3072);
    transpose_cvt<<<dim3(32, 32), 256, 0, stream>>>(Wproj, WprojT, 1024, 1024);

    gemm_bt<false, false><<<dim3(24, 32), 256, 0, stream>>>(xb, WqkvT, (void*)qkv, nullptr,
                                                            4096, 3072, 1024);
    rope_scatter<<<2048, 256, 0, stream>>>(qkv, cosT, sinT, Qr, Kr, Vt);
    attn_fwd<<<1024, 256, 0, stream>>>(Qr, Kr, Vt, aout);
    gemm_bt<true, true><<<dim3(8, 32), 256, 0, stream>>>(aout, WprojT, d_out, bproj,
                                                         4096, 1024, 1024);
}

// Round 2
// 328.100 us; speedup vs baseline: 1.4999x; 1.4999x over previous
//
#include <hip/hip_runtime.h>

typedef __attribute__((ext_vector_type(8))) short short8;
typedef __attribute__((ext_vector_type(4))) float f32x4;
typedef __attribute__((ext_vector_type(4))) unsigned short u16x4;
typedef __attribute__((ext_vector_type(8))) unsigned short u16x8;
typedef unsigned short ushort_t;

#define GLOAD16(gp, sp) __builtin_amdgcn_global_load_lds( \
    (const __attribute__((address_space(1))) void*)(gp),  \
    (__attribute__((address_space(3))) void*)(sp), 16, 0, 0)

#define MFMA(a, b, c) __builtin_amdgcn_mfma_f32_16x16x32_bf16(a, b, c, 0, 0, 0)

__device__ __forceinline__ ushort_t f2b(float f) {
    union { float f; unsigned u; } c; c.f = f;
    unsigned r = (c.u + 0x7FFFu + ((c.u >> 16) & 1u)) >> 16;
    return (ushort_t)r;
}
__device__ __forceinline__ float b2f(ushort_t u) {
    union { unsigned u; float f; } c; c.u = ((unsigned)u) << 16;
    return c.f;
}
__device__ __forceinline__ short8 packv(u16x4 a, u16x4 b) {
    u16x8 c = __builtin_shufflevector(a, b, 0, 1, 2, 3, 4, 5, 6, 7);
    union { u16x8 u; short8 s; } w; w.u = c; return w.s;
}

// ---------------- fp32 -> bf16 convert ----------------
__global__ void cvt_bf16(const float* __restrict__ in, ushort_t* __restrict__ out, int n) {
    int i = (blockIdx.x * 256 + threadIdx.x) * 4;
    if (i < n) {
        f32x4 v = *(const f32x4*)(in + i);
        u16x4 o;
        #pragma unroll
        for (int j = 0; j < 4; j++) o[j] = f2b(v[j]);
        *(u16x4*)(out + i) = o;
    }
}

// ---------------- fp32 [R][Cc] -> bf16 [Cc][R] transpose ----------------
__global__ __launch_bounds__(256) void transpose_cvt(const float* __restrict__ in,
                                                     ushort_t* __restrict__ out,
                                                     int R, int Cc) {
    __shared__ float tile[32][33];
    int tx = threadIdx.x & 31, ty = threadIdx.x >> 5;
    int c0 = blockIdx.x * 32, r0 = blockIdx.y * 32;
    #pragma unroll
    for (int i = 0; i < 32; i += 8)
        tile[ty + i][tx] = in[(size_t)(r0 + ty + i) * Cc + c0 + tx];
    __syncthreads();
    #pragma unroll
    for (int i = 0; i < 32; i += 8)
        out[(size_t)(c0 + ty + i) * R + r0 + tx] = f2b(tile[tx][ty + i]);
}

// ---------------- bf16 GEMM: C[M][N] = A[M][K] * Bt[N][K]^T ----------------
template <bool F32OUT, bool BIAS>
__global__ __launch_bounds__(256) void gemm_bt(const ushort_t* __restrict__ A,
                                               const ushort_t* __restrict__ Bt,
                                               void* __restrict__ Cout,
                                               const float* __restrict__ bias,
                                               int M, int N, int K) {
    __shared__ ushort_t lA[128 * 32];
    __shared__ ushort_t lB[128 * 32];
    const int tid = threadIdx.x;
    const int l = tid & 63, wv = tid >> 6;
    const int g = l >> 4, q16 = l & 15;
    const int m0 = blockIdx.y * 128, n0 = blockIdx.x * 128;
    const int wr = wv >> 1, wc = wv & 1;

    f32x4 acc[4][4];
    #pragma unroll
    for (int i = 0; i < 4; i++)
        #pragma unroll
        for (int j = 0; j < 4; j++) acc[i][j] = (f32x4){0.f, 0.f, 0.f, 0.f};

    const ushort_t* ga = A + (size_t)(m0 + wv * 32 + (l >> 2)) * K + (l & 3) * 8;
    const ushort_t* gb = Bt + (size_t)(n0 + wv * 32 + (l >> 2)) * K + (l & 3) * 8;
    ushort_t* sa = lA + wv * 32 * 32;
    ushort_t* sb = lB + wv * 32 * 32;

    for (int k0 = 0; k0 < K; k0 += 32) {
        __syncthreads();
        GLOAD16(ga + k0, sa);
        GLOAD16(ga + k0 + (size_t)16 * K, sa + 16 * 32);
        GLOAD16(gb + k0, sb);
        GLOAD16(gb + k0 + (size_t)16 * K, sb + 16 * 32);
        __syncthreads();

        short8 af[4], bf[4];
        #pragma unroll
        for (int mi = 0; mi < 4; mi++)
            af[mi] = *(const short8*)(lA + (wr * 64 + mi * 16 + q16) * 32 + g * 8);
        #pragma unroll
        for (int ni = 0; ni < 4; ni++)
            bf[ni] = *(const short8*)(lB + (wc * 64 + ni * 16 + q16) * 32 + g * 8);
        #pragma unroll
        for (int mi = 0; mi < 4; mi++)
            #pragma unroll
            for (int ni = 0; ni < 4; ni++)
                acc[mi][ni] = MFMA(af[mi], bf[ni], acc[mi][ni]);
    }

    #pragma unroll
    for (int ni = 0; ni < 4; ni++) {
        const int n = n0 + wc * 64 + ni * 16 + q16;
        float bv = 0.f;
        if (BIAS) bv = bias[n];
        #pragma unroll
        for (int mi = 0; mi < 4; mi++) {
            const int mbase = m0 + wr * 64 + mi * 16 + g * 4;
            #pragma unroll
            for (int r = 0; r < 4; r++) {
                if (F32OUT) {
                    ((float*)Cout)[(size_t)(mbase + r) * N + n] = acc[mi][ni][r] + bv;
                } else {
                    ((ushort_t*)Cout)[(size_t)(mbase + r) * N + n] = f2b(acc[mi][ni][r]);
                }
            }
        }
    }
}

// ---------------- RoPE + reshape ----------------
// Q gets pre-scaled by 0.125*log2(e) so attention softmax runs in pure exp2 domain.
__global__ void rope_scatter(const ushort_t* __restrict__ qkv,
                             const float* __restrict__ cosT, const float* __restrict__ sinT,
                             ushort_t* __restrict__ Qr, ushort_t* __restrict__ Kr,
                             ushort_t* __restrict__ Vt) {
    const float QS = 0.1803368801f;  // 0.125 * log2(e)
    int tid = blockIdx.x * 256 + threadIdx.x;
    {
        int dc = tid & 7;
        int bht = tid >> 3;
        int t = bht & 2047, bh = bht >> 11;
        int b = bh >> 4, h = bh & 15;
        size_t mrow = ((size_t)b * 2048 + t) * 3072;
        short8 qv = *(const short8*)(qkv + mrow + h * 64 + dc * 8);
        short8 kv = *(const short8*)(qkv + mrow + 1024 + h * 64 + dc * 8);
        f32x4 cv = *(const f32x4*)(cosT + t * 32 + dc * 4);
        f32x4 sv = *(const f32x4*)(sinT + t * 32 + dc * 4);
        short8 qo, ko;
        #pragma unroll
        for (int j = 0; j < 4; j++) {
            float qe = b2f((ushort_t)qv[2 * j]), qod = b2f((ushort_t)qv[2 * j + 1]);
            float ke = b2f((ushort_t)kv[2 * j]), kod = b2f((ushort_t)kv[2 * j + 1]);
            qo[2 * j]     = (short)f2b((qe * cv[j] - qod * sv[j]) * QS);
            qo[2 * j + 1] = (short)f2b((qe * sv[j] + qod * cv[j]) * QS);
            ko[2 * j]     = (short)f2b(ke * cv[j] - kod * sv[j]);
            ko[2 * j + 1] = (short)f2b(ke * sv[j] + kod * cv[j]);
        }
        *(short8*)(Qr + ((size_t)bh * 2048 + t) * 64 + dc * 8) = qo;
        *(short8*)(Kr + ((size_t)bh * 2048 + t) * 64 + dc * 8) = ko;
    }
    {
        int t = tid & 2047;
        int rest = tid >> 11;
        int dc = rest & 7, bh = rest >> 3;
        int b = bh >> 4, h = bh & 15;
        const ushort_t* vs = qkv + ((size_t)b * 2048 + t) * 3072 + 2048 + h * 64 + dc * 8;
        #pragma unroll
        for (int j = 0; j < 8; j++)
            Vt[((size_t)bh * 64 + dc * 8 + j) * 2048 + t] = vs[j];
    }
}

// ---------------- causal flash attention, pair-balanced ----------------
// Wave owns q-tiles p and 127-p (16 rows each): constant ~2064 keys of work per
// wave. Swapped QK^T (K rows as A, Q^T as B) keeps the P-row lane-local; PV uses
// a key-permuted contraction so St D-frags feed the PV B-frag with no shuffles.
// Double-buffered register prefetch of K/V frags hides L2 latency.

// Prefetch K (4x16B) and V (8x8B) fragments for a 32-key block into named regs.
#define PREF(P, kvb_) do {                                                     \
    const ushort_t* kp_ = Kb + ((size_t)((kvb_) + q16) << 6) + (g << 3);       \
    P##k0 = *(const short8*)kp_;                                               \
    P##k1 = *(const short8*)(kp_ + 32);                                        \
    P##k2 = *(const short8*)(kp_ + 1024);                                      \
    P##k3 = *(const short8*)(kp_ + 1056);                                      \
    const ushort_t* vp_ = Vb + ((size_t)q16 << 11) + (kvb_) + (g << 2);        \
    P##v0 = *(const u16x4*)vp_;             P##v1 = *(const u16x4*)(vp_ + 16); \
    P##v2 = *(const u16x4*)(vp_ + 32768);   P##v3 = *(const u16x4*)(vp_ + 32784); \
    P##v4 = *(const u16x4*)(vp_ + 65536);   P##v5 = *(const u16x4*)(vp_ + 65552); \
    P##v6 = *(const u16x4*)(vp_ + 98304);   P##v7 = *(const u16x4*)(vp_ + 98320); \
} while (0)

// Softmax + PV for one 16-q tile given raw (already exp2-domain) scores S0,S1.
#define TILE(S0, S1, QPOS, MSK, MR, LS, O0, O1, O2, O3, PV0, PV1, PV2, PV3, kvb_) do { \
    float sv_[8];                                                              \
    sv_[0] = S0[0]; sv_[1] = S0[1]; sv_[2] = S0[2]; sv_[3] = S0[3];            \
    sv_[4] = S1[0]; sv_[5] = S1[1]; sv_[6] = S1[2]; sv_[7] = S1[3];            \
    if (MSK) {                                                                 \
        int kb0_ = (kvb_) + (g << 2);                                          \
        _Pragma("unroll") for (int r_ = 0; r_ < 4; r_++) {                     \
            if (kb0_ + r_ > (QPOS))      sv_[r_]     = -INFINITY;              \
            if (kb0_ + 16 + r_ > (QPOS)) sv_[4 + r_] = -INFINITY;              \
        }                                                                      \
    }                                                                          \
    float sm_ = fmaxf(fmaxf(fmaxf(sv_[0], sv_[1]), fmaxf(sv_[2], sv_[3])),     \
                      fmaxf(fmaxf(sv_[4], sv_[5]), fmaxf(sv_[6], sv_[7])));    \
    sm_ = fmaxf(sm_, __shfl_xor(sm_, 16));                                     \
    sm_ = fmaxf(sm_, __shfl_xor(sm_, 32));                                     \
    if (!__all(sm_ <= MR)) {                                                   \
        float mn_ = fmaxf(MR, sm_);                                            \
        float co_ = __builtin_amdgcn_exp2f(MR - mn_);                          \
        MR = mn_; LS *= co_;                                                   \
        _Pragma("unroll") for (int r_ = 0; r_ < 4; r_++) {                     \
            O0[r_] *= co_; O1[r_] *= co_; O2[r_] *= co_; O3[r_] *= co_;        \
        }                                                                      \
    }                                                                          \
    float pp_[8];                                                              \
    _Pragma("unroll") for (int i_ = 0; i_ < 8; i_++)                           \
        pp_[i_] = __builtin_amdgcn_exp2f(sv_[i_] - MR);                        \
    LS += ((pp_[0] + pp_[1]) + (pp_[2] + pp_[3])) +                            \
          ((pp_[4] + pp_[5]) + (pp_[6] + pp_[7]));                             \
    union { short8 s; unsigned u[4]; } pu_;                                    \
    asm("v_cvt_pk_bf16_f32 %0, %1, %2" : "=v"(pu_.u[0]) : "v"(pp_[0]), "v"(pp_[1])); \
    asm("v_cvt_pk_bf16_f32 %0, %1, %2" : "=v"(pu_.u[1]) : "v"(pp_[2]), "v"(pp_[3])); \
    asm("v_cvt_pk_bf16_f32 %0, %1, %2" : "=v"(pu_.u[2]) : "v"(pp_[4]), "v"(pp_[5])); \
    asm("v_cvt_pk_bf16_f32 %0, %1, %2" : "=v"(pu_.u[3]) : "v"(pp_[6]), "v"(pp_[7])); \
    O0 = MFMA(PV0, pu_.s, O0);                                                 \
    O1 = MFMA(PV1, pu_.s, O1);                                                 \
    O2 = MFMA(PV2, pu_.s, O2);                                                 \
    O3 = MFMA(PV3, pu_.s, O3);                                                 \
} while (0)

// One 32-key block: QK for hi tile (always) + lo tile (while active), then
// softmax+PV per active tile.
#define BODY(P, kvb_) do {                                                     \
    f32x4 h0_ = {0.f, 0.f, 0.f, 0.f}, h1_ = {0.f, 0.f, 0.f, 0.f};             \
    f32x4 l0_ = {0.f, 0.f, 0.f, 0.f}, l1_ = {0.f, 0.f, 0.f, 0.f};             \
    bool lo_on_ = (kvb_) < qlo + 16;                                           \
    h0_ = MFMA(P##k0, qh0, h0_);                                               \
    h0_ = MFMA(P##k1, qh1, h0_);                                               \
    h1_ = MFMA(P##k2, qh0, h1_);                                               \
    h1_ = MFMA(P##k3, qh1, h1_);                                               \
    if (lo_on_) {                                                              \
        l0_ = MFMA(P##k0, ql0, l0_);                                           \
        l0_ = MFMA(P##k1, ql1, l0_);                                           \
        l1_ = MFMA(P##k2, ql0, l1_);                                           \
        l1_ = MFMA(P##k3, ql1, l1_);                                           \
    }                                                                          \
    short8 pv0_ = packv(P##v0, P##v1), pv1_ = packv(P##v2, P##v3);             \
    short8 pv2_ = packv(P##v4, P##v5), pv3_ = packv(P##v6, P##v7);             \
    TILE(h0_, h1_, qpos_h, (kvb_) + 31 > qhi, mr_h, ls_h,                      \
         oh0, oh1, oh2, oh3, pv0_, pv1_, pv2_, pv3_, kvb_);                    \
    if (lo_on_)                                                                \
        TILE(l0_, l1_, qpos_l, (kvb_) + 31 > qlo, mr_l, ls_l,                  \
             ol0, ol1, ol2, ol3, pv0_, pv1_, pv2_, pv3_, kvb_);                \
} while (0)

#define EPI(LS, O0, O1, O2, O3, QPOS) do {                                     \
    float l2_ = LS + __shfl_xor(LS, 16);                                       \
    l2_ += __shfl_xor(l2_, 32);                                                \
    float ri_ = 1.0f / l2_;                                                    \
    ushort_t* op_ = Aout + ((size_t)(bq * 2048 + (QPOS)) << 10) + (h << 6) + (g << 2); \
    u16x4 o_;                                                                  \
    o_[0] = f2b(O0[0] * ri_); o_[1] = f2b(O0[1] * ri_);                        \
    o_[2] = f2b(O0[2] * ri_); o_[3] = f2b(O0[3] * ri_);                        \
    *(u16x4*)op_ = o_;                                                         \
    o_[0] = f2b(O1[0] * ri_); o_[1] = f2b(O1[1] * ri_);                        \
    o_[2] = f2b(O1[2] * ri_); o_[3] = f2b(O1[3] * ri_);                        \
    *(u16x4*)(op_ + 16) = o_;                                                  \
    o_[0] = f2b(O2[0] * ri_); o_[1] = f2b(O2[1] * ri_);                        \
    o_[2] = f2b(O2[2] * ri_); o_[3] = f2b(O2[3] * ri_);                        \
    *(u16x4*)(op_ + 32) = o_;                                                  \
    o_[0] = f2b(O3[0] * ri_); o_[1] = f2b(O3[1] * ri_);                        \
    o_[2] = f2b(O3[2] * ri_); o_[3] = f2b(O3[3] * ri_);                        \
    *(u16x4*)(op_ + 48) = o_;                                                  \
} while (0)

__global__ __launch_bounds__(256) void attn_fwd(const ushort_t* __restrict__ Qr,
                                                const ushort_t* __restrict__ Kr,
                                                const ushort_t* __restrict__ Vt,
                                                ushort_t* __restrict__ Aout) {
    const int tid = threadIdx.x;
    const int l = tid & 63, wv = tid >> 6;
    const int g = l >> 4, q16 = l & 15;
    const int bh = blockIdx.x >> 4;
    const int p = (blockIdx.x & 15) * 4 + wv;     // 0..63
    const int qlo = p * 16, qhi = (127 - p) * 16; // paired tiles: constant work
    const int qpos_l = qlo + q16, qpos_h = qhi + q16;
    const int bq = bh >> 4, h = bh & 15;

    const ushort_t* Qp = Qr + ((size_t)bh * 2048) * 64;
    short8 ql0 = *(const short8*)(Qp + (size_t)qpos_l * 64 + g * 8);
    short8 ql1 = *(const short8*)(Qp + (size_t)qpos_l * 64 + g * 8 + 32);
    short8 qh0 = *(const short8*)(Qp + (size_t)qpos_h * 64 + g * 8);
    short8 qh1 = *(const short8*)(Qp + (size_t)qpos_h * 64 + g * 8 + 32);

    const ushort_t* Kb = Kr + (size_t)bh * 2048 * 64;
    const ushort_t* Vb = Vt + (size_t)bh * 64 * 2048;

    float mr_l = -INFINITY, ls_l = 0.f, mr_h = -INFINITY, ls_h = 0.f;
    f32x4 ol0 = {0.f,0.f,0.f,0.f}, ol1 = {0.f,0.f,0.f,0.f};
    f32x4 ol2 = {0.f,0.f,0.f,0.f}, ol3 = {0.f,0.f,0.f,0.f};
    f32x4 oh0 = {0.f,0.f,0.f,0.f}, oh1 = {0.f,0.f,0.f,0.f};
    f32x4 oh2 = {0.f,0.f,0.f,0.f}, oh3 = {0.f,0.f,0.f,0.f};

    short8 ak0, ak1, ak2, ak3, bk0, bk1, bk2, bk3;
    u16x4 av0, av1, av2, av3, av4, av5, av6, av7;
    u16x4 bv0, bv1, bv2, bv3, bv4, bv5, bv6, bv7;

    const int ntot = (qhi + 47) >> 5;  // hi tile needs keys < qhi+16

    PREF(a, 0);
    int ib = 0;
    for (;;) {
        if (ib + 1 < ntot) PREF(b, (ib + 1) << 5);
        BODY(a, ib << 5);
        ++ib; if (ib == ntot) break;
        if (ib + 1 < ntot) PREF(a, (ib + 1) << 5);
        BODY(b, ib << 5);
        ++ib; if (ib == ntot) break;
    }

    EPI(ls_l, ol0, ol1, ol2, ol3, qpos_l);
    EPI(ls_h, oh0, oh1, oh2, oh3, qpos_h);
}

// ---------------- launch ----------------
extern "C" void kernel_launch(void* const* d_in, const int* in_sizes, int n_in,
                              void* d_out, int out_size, void* d_ws, size_t ws_size,
                              hipStream_t stream) {
    const float* x     = (const float*)d_in[0];
    const float* Wqkv  = (const float*)d_in[1];
    const float* Wproj = (const float*)d_in[2];
    const float* bproj = (const float*)d_in[3];
    const float* cosT  = (const float*)d_in[4];
    const float* sinT  = (const float*)d_in[5];

    char* ws = (char*)d_ws;
    ushort_t* xb     = (ushort_t*)(ws);
    ushort_t* WqkvT  = (ushort_t*)(ws + (8u  << 20));
    ushort_t* WprojT = (ushort_t*)(ws + (14u << 20));
    ushort_t* qkv    = (ushort_t*)(ws + (16u << 20));
    ushort_t* Qr     = (ushort_t*)(ws + (40u << 20));
    ushort_t* Kr     = (ushort_t*)(ws + (48u << 20));
    ushort_t* Vt     = (ushort_t*)(ws + (56u << 20));
    ushort_t* aout   = (ushort_t*)(ws + (64u << 20));

    cvt_bf16<<<4096, 256, 0, stream>>>(x, xb, 4096 * 1024);
    transpose_cvt<<<dim3(96, 32), 256, 0, stream>>>(Wqkv, WqkvT, 1024, 3072);
    transpose_cvt<<<dim3(32, 32), 256, 0, stream>>>(Wproj, WprojT, 1024, 1024);

    gemm_bt<false, false><<<dim3(24, 32), 256, 0, stream>>>(xb, WqkvT, (void*)qkv, nullptr,
                                                            4096, 3072, 1024);
    rope_scatter<<<2048, 256, 0, stream>>>(qkv, cosT, sinT, Qr, Kr, Vt);
    attn_fwd<<<512, 256, 0, stream>>>(Qr, Kr, Vt, aout);
    gemm_bt<true, true><<<dim3(8, 32), 256, 0, stream>>>(aout, WprojT, d_out, bproj,
                                                         4096, 1024, 1024);
}